// Round 6
// baseline (150.911 us; speedup 1.0000x reference)
//
#include <hip/hip_runtime.h>

#define N_    64
#define HW_   240
#define H1_   120
#define H2_   60
#define C0_   3
#define C1_   32
#define C2_   64
#define C3_   128
#define HEAD_ 1280

typedef unsigned short US;
typedef short bf16x8 __attribute__((ext_vector_type(8)));
typedef float f32x16 __attribute__((ext_vector_type(16)));

__device__ __forceinline__ US f2bf(float f) {
  union { float f; unsigned u; } v; v.f = f;
  unsigned r = v.u + 0x7FFF + ((v.u >> 16) & 1);  // RNE
  return (US)(r >> 16);
}

// h1q parity-split padded NHWC bf16: [n][row 122][parity 2][xh 62][32ch].
// h1 pixel (gy,gx): row = gy+1; gx even=2m -> plane0[m]; gx odd=2m-1 -> plane1[m].
#define H1Q_ROW 3968
#define H1Q_PL  1984

__device__ __forceinline__ void gld_lds16(const void* g, void* l) {
  __builtin_amdgcn_global_load_lds(
      (const __attribute__((address_space(1))) unsigned int*)g,
      (__attribute__((address_space(3))) unsigned int*)l, 16, 0, 0);
}

// ---------------------------------------------------------------------------
// K0: prep — zero h1q pad cells (uint4); w1 -> wt1 [ky][kx][oc][ic] bf16;
// w2 -> wt2 [oc][ic] bf16; w_stem -> wt0 [oc][k32] bf16 (k>=27 zero);
// zero gap. (R16, unchanged.)
// ---------------------------------------------------------------------------
#define ZCHN   368                 // zero-chunks per n (124+124+120)
#define ZTOT   (64 * ZCHN * 4)     // 94208
__global__ __launch_bounds__(256) void k0_prep(
    const float* __restrict__ w1, const float* __restrict__ w2,
    const float* __restrict__ w0,
    US* __restrict__ h1q, US* __restrict__ wt1, US* __restrict__ wt2,
    US* __restrict__ wt0, float* __restrict__ gap) {
  int gid = blockIdx.x * 256 + threadIdx.x;
  if (gid < ZTOT) {
    int c = gid >> 2, q = gid & 3;
    int n = c / ZCHN, cc = c % ZCHN;
    long off; int y;
    if (cc < 124)      { y = 0;   off = (long)cc * 32; }
    else if (cc < 248) { y = 121; off = (long)(cc - 124) * 32; }
    else               { y = cc - 247; off = H1Q_PL; }   // p1 m=0, rows 1..120
    uint4 z; z.x = z.y = z.z = z.w = 0u;
    *(uint4*)(h1q + ((long)(n * 122 + y)) * H1Q_ROW + off + q * 8) = z;
  } else if (gid < ZTOT + 18432) {
    int e = gid - ZTOT;                       // w1 flat [oc][ic][ky][kx]
    int oc = e / 288, ic = (e / 9) % 32, ky = (e / 3) % 3, kx = e % 3;
    wt1[((ky * 3 + kx) * 64 + oc) * 32 + ic] = f2bf(w1[e]);
  } else if (gid < ZTOT + 18432 + 8192) {
    int e = gid - (ZTOT + 18432);
    wt2[e] = f2bf(w2[e]);
  } else if (gid < ZTOT + 18432 + 8192 + 1024) {
    int e = gid - (ZTOT + 18432 + 8192);      // e = oc*32 + k
    int oc = e >> 5, k = e & 31;
    wt0[e] = (k < 27) ? f2bf(w0[oc * 27 + k]) : (US)0;
  } else if (gid < ZTOT + 18432 + 8192 + 1024 + 8192) {
    gap[gid - (ZTOT + 18432 + 8192 + 1024)] = 0.f;
  }
}

// ---------------------------------------------------------------------------
// K1 (R19): stem conv 3->32, TWO output rows per block (grid 60x64).
// Input rows 4Y-1..4Y+3 (5 rows x 3 ch = 15 segs) staged once via
// global_load_lds; rows 4Y+1 shared by both outputs (-17% x reads), block
// count halved, per-block fixed costs amortized 2x. Per wave: 2 tiles
// (row0 quarter w, row1 quarter w) = 4 MFMAs. Math bit-identical to R18.
// LDS 14880(xs) + 16384(ot) = 31264 B -> 5 blocks/CU.
// ---------------------------------------------------------------------------
#define XSW 248
__global__ __launch_bounds__(256) void k1_mfma(
    const float* __restrict__ x, const US* __restrict__ wt0,
    const float* __restrict__ alpha, const float* __restrict__ beta,
    US* __restrict__ h1q) {
  __shared__ __align__(16) float xs[15 * XSW];  // [seg = ic*5 + r5][248]
  __shared__ US ot[256 * 32];                   // [rowsel*128 + px4][oc]
  int Y = blockIdx.x, n = blockIdx.y;           // output rows 2Y, 2Y+1
  int iyb = 4 * Y - 1;                          // input row for r5=0
  const float* xn = x + (long)n * C0_ * HW_ * HW_;
  int t = threadIdx.x, w = t >> 6, l = t & 63;

  // boundary zeros: cols 0..3 and 244..247 per seg (15 segs)
  if (t < 30) {
    int seg = t >> 1, end = t & 1;
    float4 z; z.x = z.y = z.z = z.w = 0.f;
    *(float4*)(xs + seg * XSW + (end ? 244 : 0)) = z;
  }
  // iy<0 (only Y==0, r5==0 -> segs 0,5,10): pre-zero interior
  if (Y == 0) {
    float4 z; z.x = z.y = z.z = z.w = 0.f;
    for (int e = t; e < 180; e += 256) {
      int m = e % 60, icz = e / 60;
      *(float4*)(xs + (icz * 5) * XSW + 4 + 4 * m) = z;
    }
  }
  __syncthreads();   // zeros visible before async staging

  // async stage 15 segs (wave-uniform seg; lanes 0..59, 16 B each)
  for (int sgi = w; sgi < 15; sgi += 4) {
    int ic = sgi / 5, r5 = sgi - (sgi / 5) * 5;
    int iy = iyb + r5;                 // wave-uniform; max 4*59+3=239
    if (iy >= 0 && l < 60)
      gld_lds16((const char*)(xn + (long)ic * HW_ * HW_ + (long)iy * HW_) +
                    l * 16,
                (char*)(xs + sgi * XSW + 4) + l * 16);
  }
  __syncthreads();   // drains vmcnt

  int lane31 = l & 31, half = l >> 5;
  const US* wb = wt0 + lane31 * 32 + half * 8;   // oc = lane31
  bf16x8 b0 = *(const bf16x8*)(wb);
  bf16x8 b1 = *(const bf16x8*)(wb + 16);
  int oc = lane31;
  float al = alpha[oc], be = beta[oc];

#pragma unroll
  for (int rowsel = 0; rowsel < 2; rowsel++) {
    int ox = w * 32 + lane31;                    // quarter = w
    int oxc = ox < H1_ ? ox : (H1_ - 1);
    // A fragments: k = m*16 + half*8 + j; xs[(ic*5 + 2*rowsel + ky)][3+2oxc+kx]
    float fa[16];
#pragma unroll
    for (int m = 0; m < 2; m++)
#pragma unroll
      for (int j = 0; j < 8; j++) {
        int k = m * 16 + half * 8 + j;
        float v = 0.f;
        if (k < 27) {
          int ic = k / 9, rem = k - ic * 9;
          int ky = rem / 3, kx = rem - ky * 3;
          v = xs[(ic * 5 + 2 * rowsel + ky) * XSW + 3 + 2 * oxc + kx];
        }
        fa[m * 8 + j] = v;
      }
    bf16x8 a0, a1;
#pragma unroll
    for (int j = 0; j < 8; j++) {
      a0[j] = (short)f2bf(fa[j]);
      a1[j] = (short)f2bf(fa[8 + j]);
    }
    f32x16 acc;
#pragma unroll
    for (int i = 0; i < 16; i++) acc[i] = 0.f;
    acc = __builtin_amdgcn_mfma_f32_32x32x16_bf16(a0, b0, acc, 0, 0, 0);
    acc = __builtin_amdgcn_mfma_f32_32x32x16_bf16(a1, b1, acc, 0, 0, 0);
#pragma unroll
    for (int r = 0; r < 16; r++) {
      int row = (r & 3) + 8 * (r >> 2) + 4 * half;   // px within tile
      float v = fmaxf(fmaf(acc[r], al, be), 0.f);
      ot[(rowsel * 128 + w * 32 + row) * 32 + oc] = f2bf(v);
    }
  }
  __syncthreads();

  // store 2 rows x 120 px x 64 B, parity-split; 960 uint4 total
  for (int u = t; u < 960; u += 256) {
    int rowsel = u / 480, uu = u - rowsel * 480;
    int px = uu >> 2, q = uu & 3;
    int pl = px & 1;
    int m = (px + 1) >> 1;
    long rowb = ((long)(n * 122 + 2 * Y + rowsel + 1)) * H1Q_ROW;
    long addr = rowb + (pl ? H1Q_PL : 0) + (long)m * 32 + q * 8;
    *(uint4*)(h1q + addr) = *(const uint4*)(ot + (rowsel * 128 + px) * 32 + q * 8);
  }
}

// ---------------------------------------------------------------------------
// K2 (R19): ring-5 persistent pipelined conv2+conv3+GAP. grid (8,96) = 768
// blocks = 3/CU (launch_bounds (256,3)); 12 groups x 5 rows per n. Ring of
// 5 slots is exactly the live window {2y..2y+4} (distinct mod 5; prefetch
// slots disjoint from compute slots each phase — audited). LDS 40960+9216 =
// 50176 B -> 3 blocks/CU, +50% latency overlap vs R16's 2. Staging zero-
// waste (11 rows per 5-row group). Weights hoisted; loop has no global loads.
// ---------------------------------------------------------------------------
#define TS 72
__global__ __launch_bounds__(256, 3) void k2_fused(
    const US* __restrict__ h1q, const US* __restrict__ wt1,
    const US* __restrict__ wt2,
    const float* __restrict__ a1, const float* __restrict__ b1,
    const float* __restrict__ a2, const float* __restrict__ b2,
    float* __restrict__ gap) {
  __shared__ __align__(16) US st[5 * 4096];    // 40960 B: 5 row-slots (swz)
  __shared__ __align__(16) US tile[64 * TS];   // 9216 B: conv2 out [px][oc]
  int t = threadIdx.x, w = t >> 6, l = t & 63;
  int lane31 = l & 31, half = l >> 5;

  // XCD x (= blockIdx.x, x-major dispatch) handles n in [8x, 8x+8)
  int n = 8 * blockIdx.x + (blockIdx.y & 7);
  int bxr = blockIdx.y >> 3;                   // row-group 0..11
  int y0 = bxr * 5;                            // 5 rows per group

  const char* nb = (const char*)(h1q + (long)(n * 122) * H1Q_ROW);

  // ---- hoist all weights / BN params to registers (loop-invariant) ----
  int wm = w & 1, wn = w >> 1;                 // stage-A roles
  int oc = wn * 32 + lane31;
  int pt = w & 1, og = w >> 1;                 // conv3 roles
  bf16x8 wA[9][2];
#pragma unroll
  for (int kk = 0; kk < 9; kk++)
#pragma unroll
    for (int c = 0; c < 2; c++)
      wA[kk][c] = *(const bf16x8*)(wt1 + (kk * 64 + oc) * 32 + half * 8 + c * 16);
  bf16x8 wB[2][4];
  float al2[2], be2[2];
#pragma unroll
  for (int nt = 0; nt < 2; nt++) {
    int oc2 = (og * 2 + nt) * 32 + lane31;
#pragma unroll
    for (int c = 0; c < 4; c++)
      wB[nt][c] = *(const bf16x8*)(wt2 + oc2 * 64 + half * 8 + c * 16);
    al2[nt] = a2[oc2]; be2[nt] = b2[oc2];
  }
  float al1 = a1[oc], be1 = b1[oc];

  // per-thread invariant A-read offsets (swizzled, within-row US units)
  int px = wm * 32 + lane31;
  int xx = px < 60 ? px : 59;
  int abase = xx * 32 + half * 8;
  int usofs[3][2];
#pragma unroll
  for (int kx = 0; kx < 3; kx++)
#pragma unroll
    for (int c = 0; c < 2; c++) {
      int uo = (kx == 1 ? 0 : (kx == 0 ? 1984 : 2016)) + abase + c * 16;
      usofs[kx][c] = uo ^ (((uo >> 6) & 7) << 3);
    }

  // ---- prologue: stage rows 2y0..2y0+2, 512 chunks (8 KB) per row ----
#pragma unroll
  for (int i = 0; i < 6; i++) {
    int c = i * 256 + t;                  // 1536 = 3 rows * 512 chunks
    int rw = c >> 9;                      // wave-uniform (512 % 64 == 0)
    int b = (c & 511) * 16;
    int sb = b ^ (((b >> 7) & 7) << 4);
    int r = 2 * y0 + rw;
    gld_lds16(nb + (long)r * 7936 + sb, (char*)st + (r % 5) * 8192 + b);
  }
  __syncthreads();

  for (int iy = 0; iy < 5; iy++) {
    int y = y0 + iy;
    // ---- issue next-2-row stage early (hidden under stage-A MFMAs) ----
    if (iy < 4) {
#pragma unroll
      for (int i = 0; i < 4; i++) {
        int c = i * 256 + t;              // 1024 = 2 rows * 512 chunks
        int rw = c >> 9;                  // wave-uniform
        int b = (c & 511) * 16;
        int sb = b ^ (((b >> 7) & 7) << 4);
        int r = 2 * y + 3 + rw;           // rows 2y+3, 2y+4 (slots disjoint
        gld_lds16(nb + (long)r * 7936 + sb,  // from compute rows 2y..2y+2)
                  (char*)st + (r % 5) * 8192 + b);
      }
    }

    // ---- stage A: conv2 3x3 s2, 32->64, from LDS ring ----
    f32x16 acc;
#pragma unroll
    for (int i = 0; i < 16; i++) acc[i] = 0.f;
#pragma unroll
    for (int ky = 0; ky < 3; ky++) {
      int r = 2 * y + ky;
      int sb5 = (r % 5) * 4096;
#pragma unroll
      for (int kx = 0; kx < 3; kx++) {
#pragma unroll
        for (int c = 0; c < 2; c++) {
          bf16x8 av = *(const bf16x8*)(st + sb5 + usofs[kx][c]);
          acc = __builtin_amdgcn_mfma_f32_32x32x16_bf16(av, wA[ky * 3 + kx][c],
                                                        acc, 0, 0, 0);
        }
      }
    }
#pragma unroll
    for (int r = 0; r < 16; r++) {
      int row = (r & 3) + 8 * (r >> 2) + 4 * half;
      tile[(wm * 32 + row) * TS + oc] = f2bf(fmaxf(fmaf(acc[r], al1, be1), 0.f));
    }
    __syncthreads();   // tile ready; also drains prefetch vmcnt (has cover)

    // ---- conv3 1x1 64->128 + BN/ReLU + GAP ----
    const US* ab = tile + (pt * 32 + lane31) * TS + half * 8;
    bf16x8 af[4];
#pragma unroll
    for (int c = 0; c < 4; c++) af[c] = *(const bf16x8*)(ab + c * 16);

#pragma unroll
    for (int nt = 0; nt < 2; nt++) {
      int oc2 = (og * 2 + nt) * 32 + lane31;
      f32x16 acc2;
#pragma unroll
      for (int i = 0; i < 16; i++) acc2[i] = 0.f;
#pragma unroll
      for (int c = 0; c < 4; c++)
        acc2 = __builtin_amdgcn_mfma_f32_32x32x16_bf16(af[c], wB[nt][c], acc2,
                                                       0, 0, 0);
      float s = 0.f;
      if (pt == 0) {
#pragma unroll
        for (int r = 0; r < 16; r++) s += fmaxf(fmaf(acc2[r], al2[nt], be2[nt]), 0.f);
      } else {
#pragma unroll
        for (int r = 0; r < 16; r++) {
          int row = (r & 3) + 8 * (r >> 2) + 4 * half;
          if (32 + row < 60) s += fmaxf(fmaf(acc2[r], al2[nt], be2[nt]), 0.f);
        }
      }
      s += __shfl_xor(s, 32);
      if (half == 0) atomicAdd(gap + n * C3_ + oc2, s);
    }
    __syncthreads();   // protect tile + ring slots for next iteration
  }
}

// ---------------------------------------------------------------------------
// K4 (R16, unchanged): head — 8 n's per block, wh reused. grid (5, 8).
// ---------------------------------------------------------------------------
__global__ __launch_bounds__(256) void k4_head(
    const float* __restrict__ gap, const float* __restrict__ wh,
    const float* __restrict__ alpha, const float* __restrict__ beta,
    float* __restrict__ out) {
  __shared__ float g[8 * C3_];
  int n0 = blockIdx.y * 8;
  int t = threadIdx.x;
  for (int e = t; e < 8 * C3_; e += 256)
    g[e] = gap[n0 * C3_ + e] * (1.f / 3600.f);
  __syncthreads();
  int o = blockIdx.x * 256 + t;
  const float* wr = wh + (long)o * C3_;
  float acc[8];
#pragma unroll
  for (int i = 0; i < 8; i++) acc[i] = 0.f;
#pragma unroll 4
  for (int c = 0; c < C3_; c += 4) {
    float4 wv = *(const float4*)(wr + c);
#pragma unroll
    for (int i = 0; i < 8; i++) {
      const float* gi = g + i * C3_ + c;
      acc[i] = fmaf(wv.x, gi[0], acc[i]);
      acc[i] = fmaf(wv.y, gi[1], acc[i]);
      acc[i] = fmaf(wv.z, gi[2], acc[i]);
      acc[i] = fmaf(wv.w, gi[3], acc[i]);
    }
  }
  float al = alpha[o], be = beta[o];
#pragma unroll
  for (int i = 0; i < 8; i++)
    out[(n0 + i) * HEAD_ + o] = fmaxf(fmaf(acc[i], al, be), 0.f);
}

// ---------------------------------------------------------------------------
extern "C" void kernel_launch(void* const* d_in, const int* in_sizes, int n_in,
                              void* d_out, int out_size, void* d_ws,
                              size_t ws_size, hipStream_t stream) {
  const float* x      = (const float*)d_in[0];
  const float* w_stem = (const float*)d_in[1];
  const float* a_stem = (const float*)d_in[2];
  const float* b_stem = (const float*)d_in[3];
  const float* w1     = (const float*)d_in[4];
  const float* a1     = (const float*)d_in[5];
  const float* b1     = (const float*)d_in[6];
  const float* w2     = (const float*)d_in[7];
  const float* a2     = (const float*)d_in[8];
  const float* b2     = (const float*)d_in[9];
  const float* wh     = (const float*)d_in[10];
  const float* ah     = (const float*)d_in[11];
  const float* bh     = (const float*)d_in[12];
  float* out = (float*)d_out;

  US* h1q = (US*)d_ws;                                   // 64*122*3968
  US* wt1 = h1q + (size_t)N_ * 122 * H1Q_ROW;            // 9*64*32
  US* wt2 = wt1 + 9 * 64 * 32;                           // 128*64
  US* wt0 = wt2 + C3_ * C2_;                             // 32*32
  float* gap = (float*)(wt0 + 1024);                     // 64*128 f32

  {  // K0 prep
    int total = ZTOT + 18432 + 8192 + 1024 + 8192;
    k0_prep<<<(total + 255) / 256, 256, 0, stream>>>(w1, w2, w_stem, h1q,
                                                     wt1, wt2, wt0, gap);
  }
  {  // K1 MFMA stem: 2 output rows per block
    dim3 grid(H2_, N_);
    k1_mfma<<<grid, 256, 0, stream>>>(x, wt0, a_stem, b_stem, h1q);
  }
  {  // K2 ring-5 pipelined conv2+conv3+GAP, 3 blocks/CU
    dim3 grid(8, 96);
    k2_fused<<<grid, 256, 0, stream>>>(h1q, wt1, wt2, a1, b1, a2, b2, gap);
  }
  {  // K4: 8 n's per block, wh reused
    dim3 grid(HEAD_ / 256, 8);
    k4_head<<<grid, 256, 0, stream>>>(gap, wh, ah, bh, out);
  }
}

// Round 7
// 150.763 us; speedup vs baseline: 1.0010x; 1.0010x over previous
//
#include <hip/hip_runtime.h>

#define N_    64
#define HW_   240
#define H1_   120
#define H2_   60
#define C0_   3
#define C1_   32
#define C2_   64
#define C3_   128
#define HEAD_ 1280

typedef unsigned short US;
typedef short bf16x8 __attribute__((ext_vector_type(8)));
typedef float f32x16 __attribute__((ext_vector_type(16)));

__device__ __forceinline__ US f2bf(float f) {
  union { float f; unsigned u; } v; v.f = f;
  unsigned r = v.u + 0x7FFF + ((v.u >> 16) & 1);  // RNE
  return (US)(r >> 16);
}

// h1q parity-split padded NHWC bf16: [n][row 122][parity 2][xh 62][32ch].
// h1 pixel (gy,gx): row = gy+1; gx even=2m -> plane0[m]; gx odd=2m-1 -> plane1[m].
#define H1Q_ROW 3968
#define H1Q_PL  1984

__device__ __forceinline__ void gld_lds16(const void* g, void* l) {
  __builtin_amdgcn_global_load_lds(
      (const __attribute__((address_space(1))) unsigned int*)g,
      (__attribute__((address_space(3))) unsigned int*)l, 16, 0, 0);
}

// ---------------------------------------------------------------------------
// K0: prep — zero h1q pad cells (uint4); w1 -> wt1 [ky][kx][oc][ic] bf16;
// w2 -> wt2 [oc][ic] bf16; w_stem -> wt0 [oc][k32] bf16 (k>=27 zero);
// zero gap. (R16, unchanged.)
// ---------------------------------------------------------------------------
#define ZCHN   368                 // zero-chunks per n (124+124+120)
#define ZTOT   (64 * ZCHN * 4)     // 94208
__global__ __launch_bounds__(256) void k0_prep(
    const float* __restrict__ w1, const float* __restrict__ w2,
    const float* __restrict__ w0,
    US* __restrict__ h1q, US* __restrict__ wt1, US* __restrict__ wt2,
    US* __restrict__ wt0, float* __restrict__ gap) {
  int gid = blockIdx.x * 256 + threadIdx.x;
  if (gid < ZTOT) {
    int c = gid >> 2, q = gid & 3;
    int n = c / ZCHN, cc = c % ZCHN;
    long off; int y;
    if (cc < 124)      { y = 0;   off = (long)cc * 32; }
    else if (cc < 248) { y = 121; off = (long)(cc - 124) * 32; }
    else               { y = cc - 247; off = H1Q_PL; }   // p1 m=0, rows 1..120
    uint4 z; z.x = z.y = z.z = z.w = 0u;
    *(uint4*)(h1q + ((long)(n * 122 + y)) * H1Q_ROW + off + q * 8) = z;
  } else if (gid < ZTOT + 18432) {
    int e = gid - ZTOT;                       // w1 flat [oc][ic][ky][kx]
    int oc = e / 288, ic = (e / 9) % 32, ky = (e / 3) % 3, kx = e % 3;
    wt1[((ky * 3 + kx) * 64 + oc) * 32 + ic] = f2bf(w1[e]);
  } else if (gid < ZTOT + 18432 + 8192) {
    int e = gid - (ZTOT + 18432);
    wt2[e] = f2bf(w2[e]);
  } else if (gid < ZTOT + 18432 + 8192 + 1024) {
    int e = gid - (ZTOT + 18432 + 8192);      // e = oc*32 + k
    int oc = e >> 5, k = e & 31;
    wt0[e] = (k < 27) ? f2bf(w0[oc * 27 + k]) : (US)0;
  } else if (gid < ZTOT + 18432 + 8192 + 1024 + 8192) {
    gap[gid - (ZTOT + 18432 + 8192 + 1024)] = 0.f;
  }
}

// ---------------------------------------------------------------------------
// K1 (R18, reverted from R19): stem conv 3->32 via MFMA im2col, 1 output
// row per block (grid 120x64), global_load_lds x staging. Known-good 148.7.
// ---------------------------------------------------------------------------
#define XSW 248
__global__ __launch_bounds__(256) void k1_mfma(
    const float* __restrict__ x, const US* __restrict__ wt0,
    const float* __restrict__ alpha, const float* __restrict__ beta,
    US* __restrict__ h1q) {
  __shared__ __align__(16) float xs[3 * 3 * XSW];  // [seg=ic*3+r][248]
  __shared__ US ot[128 * 32];         // [px][oc] bf16
  int y = blockIdx.x, n = blockIdx.y;
  int iy0 = 2 * y - 1;
  const float* xn = x + (long)n * C0_ * HW_ * HW_;
  int t = threadIdx.x, w = t >> 6, l = t & 63;

  // boundary zeros: cols 0..3 and 244..247 per seg
  if (t < 18) {
    int seg = t >> 1, end = t & 1;
    float4 z; z.x = z.y = z.z = z.w = 0.f;
    *(float4*)(xs + seg * XSW + (end ? 244 : 0)) = z;
  }
  // iy<0 rows (only y==0, segs r==0): pre-zero interior
  if (y == 0) {
    float4 z; z.x = z.y = z.z = z.w = 0.f;
    for (int e = t; e < 180; e += 256) {
      int m = e % 60, icz = e / 60;
      *(float4*)(xs + (icz * 3) * XSW + 4 + 4 * m) = z;
    }
  }
  __syncthreads();   // zeros visible before async staging overlaps

  // async stage: seg (wave-uniform) = w, w+4, w+8; 60 lanes x 16 B each
  for (int sgi = w; sgi < 9; sgi += 4) {
    int ic = sgi / 3, r = sgi - (sgi / 3) * 3;
    int iy = iy0 + r;                  // wave-uniform
    if (iy >= 0 && l < 60)
      gld_lds16((const char*)(xn + (long)ic * HW_ * HW_ + (long)iy * HW_) +
                    l * 16,
                (char*)(xs + sgi * XSW + 4) + l * 16);
  }
  __syncthreads();   // drains vmcnt

  int wv = w;
  int lane31 = l & 31, half = l >> 5;
  int ox = wv * 32 + lane31;
  int oxc = ox < H1_ ? ox : (H1_ - 1);

  // A fragments: k = m*16 + half*8 + j; value = xs[seg(k)][3 + 2*oxc + kx]
  float fa[16];
#pragma unroll
  for (int m = 0; m < 2; m++)
#pragma unroll
    for (int j = 0; j < 8; j++) {
      int k = m * 16 + half * 8 + j;
      float v = 0.f;
      if (k < 27) {
        int ic = k / 9, rem = k - ic * 9;
        int ky = rem / 3, kx = rem - ky * 3;
        v = xs[(ic * 3 + ky) * XSW + 3 + 2 * oxc + kx];
      }
      fa[m * 8 + j] = v;
    }
  bf16x8 a0, a1;
#pragma unroll
  for (int j = 0; j < 8; j++) {
    a0[j] = (short)f2bf(fa[j]);
    a1[j] = (short)f2bf(fa[8 + j]);
  }
  const US* wb = wt0 + lane31 * 32 + half * 8;   // oc = lane31
  bf16x8 b0 = *(const bf16x8*)(wb);
  bf16x8 b1 = *(const bf16x8*)(wb + 16);

  f32x16 acc;
#pragma unroll
  for (int i = 0; i < 16; i++) acc[i] = 0.f;
  acc = __builtin_amdgcn_mfma_f32_32x32x16_bf16(a0, b0, acc, 0, 0, 0);
  acc = __builtin_amdgcn_mfma_f32_32x32x16_bf16(a1, b1, acc, 0, 0, 0);

  int oc = lane31;
  float al = alpha[oc], be = beta[oc];
#pragma unroll
  for (int r = 0; r < 16; r++) {
    int row = (r & 3) + 8 * (r >> 2) + 4 * half;   // px within tile
    float v = fmaxf(fmaf(acc[r], al, be), 0.f);
    ot[(wv * 32 + row) * 32 + oc] = f2bf(v);
  }
  __syncthreads();

  // store 120 px * 64 B as parity-split full chunks; 480 uint4 total
  long rowb = ((long)(n * 122 + y + 1)) * H1Q_ROW;
  for (int u = t; u < 480; u += 256) {
    int px = u >> 2, q = u & 3;
    int pl = px & 1;
    int m = (px + 1) >> 1;
    long addr = rowb + (pl ? H1Q_PL : 0) + (long)m * 32 + q * 8;
    *(uint4*)(h1q + addr) = *(const uint4*)(ot + px * 32 + q * 8);
  }
}

// ---------------------------------------------------------------------------
// K2 (R20): ring-8 counted-vmcnt pipelined conv2+conv3+GAP (T4 applied).
// grid (8,64) = 512 blocks = 2/CU, bound (256,2). Changes vs R16:
//  - GAP partial sums accumulated in registers (gsum[2]); ONE atomicAdd per
//    block at the end -> loop's only vmem ops are prefetch gld_lds, making
//    vmcnt counting exact.
//  - 2-iteration-ahead prefetch (rows 2y+5,2y+6 for iter y+2) into ring-8
//    (65536 B); end-of-iter sync = s_waitcnt vmcnt(4) + raw s_barrier
//    (retires iter-(y-1)'s prefetch, keeps this iter's 4 in flight across
//    the barrier); mid-iter barrier waits lgkmcnt(0) only. No vmcnt(0) in
//    the steady-state loop — removes ~700cy/iter of exposed L3 latency.
//  Slot audit: live rows 2y..2y+8 at issue time = exactly 8 distinct mod 8;
//  prefetch slots disjoint from compute slots every phase; slot reuse only
//  after its last reader passed a barrier. Tail: iy=ny-2 waits vmcnt(0)
//  (2 iters of cover); last iter skips the end barrier.
// ---------------------------------------------------------------------------
#define TS 72
__global__ __launch_bounds__(256, 2) void k2_fused(
    const US* __restrict__ h1q, const US* __restrict__ wt1,
    const US* __restrict__ wt2,
    const float* __restrict__ a1, const float* __restrict__ b1,
    const float* __restrict__ a2, const float* __restrict__ b2,
    float* __restrict__ gap) {
  __shared__ __align__(16) US st[8 * 4096];    // 65536 B: ring-8 (swz)
  __shared__ __align__(16) US tile[64 * TS];   // 9216 B: conv2 out [px][oc]
  int t = threadIdx.x, w = t >> 6, l = t & 63;
  int lane31 = l & 31, half = l >> 5;

  // XCD x (= blockIdx.x, x-major dispatch) handles n in [8x, 8x+8)
  int n = 8 * blockIdx.x + (blockIdx.y & 7);
  int bxr = blockIdx.y >> 3;                   // row-group 0..7
  int ny = bxr < 4 ? 8 : 7;
  int y0 = bxr < 4 ? bxr * 8 : 32 + (bxr - 4) * 7;

  const char* nb = (const char*)(h1q + (long)(n * 122) * H1Q_ROW);

  // ---- hoist all weights / BN params to registers (loop-invariant) ----
  int wm = w & 1, wn = w >> 1;                 // stage-A roles
  int oc = wn * 32 + lane31;
  int pt = w & 1, og = w >> 1;                 // conv3 roles
  bf16x8 wA[9][2];
#pragma unroll
  for (int kk = 0; kk < 9; kk++)
#pragma unroll
    for (int c = 0; c < 2; c++)
      wA[kk][c] = *(const bf16x8*)(wt1 + (kk * 64 + oc) * 32 + half * 8 + c * 16);
  bf16x8 wB[2][4];
  float al2[2], be2[2];
#pragma unroll
  for (int nt = 0; nt < 2; nt++) {
    int oc2 = (og * 2 + nt) * 32 + lane31;
#pragma unroll
    for (int c = 0; c < 4; c++)
      wB[nt][c] = *(const bf16x8*)(wt2 + oc2 * 64 + half * 8 + c * 16);
    al2[nt] = a2[oc2]; be2[nt] = b2[oc2];
  }
  float al1 = a1[oc], be1 = b1[oc];
  float gsum[2] = {0.f, 0.f};

  // per-thread invariant A-read offsets (swizzled, within-row US units)
  int px = wm * 32 + lane31;
  int xx = px < 60 ? px : 59;
  int abase = xx * 32 + half * 8;
  int usofs[3][2];
#pragma unroll
  for (int kx = 0; kx < 3; kx++)
#pragma unroll
    for (int c = 0; c < 2; c++) {
      int uo = (kx == 1 ? 0 : (kx == 0 ? 1984 : 2016)) + abase + c * 16;
      usofs[kx][c] = uo ^ (((uo >> 6) & 7) << 3);
    }

  // ---- prologue: stage rows 2y0..2y0+4, 512 chunks (8 KB) per row ----
#pragma unroll
  for (int i = 0; i < 10; i++) {
    int c = i * 256 + t;                  // 2560 = 5 rows * 512 chunks
    int rw = c >> 9;                      // wave-uniform (512 % 64 == 0)
    int b = (c & 511) * 16;
    int sb = b ^ (((b >> 7) & 7) << 4);
    int r = 2 * y0 + rw;
    gld_lds16(nb + (long)r * 7936 + sb, (char*)st + (r & 7) * 8192 + b);
  }
  asm volatile("s_waitcnt vmcnt(0)" ::: "memory");
  __builtin_amdgcn_s_barrier();
  __builtin_amdgcn_sched_barrier(0);

  for (int iy = 0; iy < ny; iy++) {
    int y = y0 + iy;
    // ---- prefetch rows 2y+5, 2y+6 (consumed at iter iy+2) ----
    if (iy + 2 < ny) {
#pragma unroll
      for (int i = 0; i < 4; i++) {
        int c = i * 256 + t;              // 1024 = 2 rows * 512 chunks
        int rw = c >> 9;                  // wave-uniform
        int b = (c & 511) * 16;
        int sb = b ^ (((b >> 7) & 7) << 4);
        int r = 2 * y + 5 + rw;
        gld_lds16(nb + (long)r * 7936 + sb, (char*)st + (r & 7) * 8192 + b);
      }
    }

    // ---- conv2 3x3 s2, 32->64, from LDS ring ----
    f32x16 acc;
#pragma unroll
    for (int i = 0; i < 16; i++) acc[i] = 0.f;
#pragma unroll
    for (int ky = 0; ky < 3; ky++) {
      int r = 2 * y + ky;
      int sb8 = (r & 7) * 4096;
#pragma unroll
      for (int kx = 0; kx < 3; kx++) {
#pragma unroll
        for (int c = 0; c < 2; c++) {
          bf16x8 av = *(const bf16x8*)(st + sb8 + usofs[kx][c]);
          acc = __builtin_amdgcn_mfma_f32_32x32x16_bf16(av, wA[ky * 3 + kx][c],
                                                        acc, 0, 0, 0);
        }
      }
    }
#pragma unroll
    for (int r = 0; r < 16; r++) {
      int row = (r & 3) + 8 * (r >> 2) + 4 * half;
      tile[(wm * 32 + row) * TS + oc] = f2bf(fmaxf(fmaf(acc[r], al1, be1), 0.f));
    }
    // mid-iter barrier: LDS visibility only — prefetch stays in flight
    asm volatile("s_waitcnt lgkmcnt(0)" ::: "memory");
    __builtin_amdgcn_s_barrier();
    __builtin_amdgcn_sched_barrier(0);

    // ---- conv3 1x1 64->128 + BN/ReLU + GAP (register accumulation) ----
    const US* ab = tile + (pt * 32 + lane31) * TS + half * 8;
    bf16x8 af[4];
#pragma unroll
    for (int c = 0; c < 4; c++) af[c] = *(const bf16x8*)(ab + c * 16);

#pragma unroll
    for (int nt = 0; nt < 2; nt++) {
      f32x16 acc2;
#pragma unroll
      for (int i = 0; i < 16; i++) acc2[i] = 0.f;
#pragma unroll
      for (int c = 0; c < 4; c++)
        acc2 = __builtin_amdgcn_mfma_f32_32x32x16_bf16(af[c], wB[nt][c], acc2,
                                                       0, 0, 0);
      float s = 0.f;
      if (pt == 0) {
#pragma unroll
        for (int r = 0; r < 16; r++) s += fmaxf(fmaf(acc2[r], al2[nt], be2[nt]), 0.f);
      } else {
#pragma unroll
        for (int r = 0; r < 16; r++) {
          int row = (r & 3) + 8 * (r >> 2) + 4 * half;
          if (32 + row < 60) s += fmaxf(fmaf(acc2[r], al2[nt], be2[nt]), 0.f);
        }
      }
      gsum[nt] += s;
    }

    // end-of-iter: retire previous iter's prefetch, keep this iter's 4
    if (iy + 1 < ny) {
      if (iy + 2 < ny)
        asm volatile("s_waitcnt vmcnt(4) lgkmcnt(0)" ::: "memory");
      else
        asm volatile("s_waitcnt vmcnt(0) lgkmcnt(0)" ::: "memory");
      __builtin_amdgcn_s_barrier();
      __builtin_amdgcn_sched_barrier(0);
    }
  }

  // ---- one atomic commit per block ----
#pragma unroll
  for (int nt = 0; nt < 2; nt++) {
    float s = gsum[nt];
    s += __shfl_xor(s, 32);
    if (half == 0) {
      int oc2 = (og * 2 + nt) * 32 + lane31;
      atomicAdd(gap + n * C3_ + oc2, s);
    }
  }
}

// ---------------------------------------------------------------------------
// K4 (R16, unchanged): head — 8 n's per block, wh reused. grid (5, 8).
// ---------------------------------------------------------------------------
__global__ __launch_bounds__(256) void k4_head(
    const float* __restrict__ gap, const float* __restrict__ wh,
    const float* __restrict__ alpha, const float* __restrict__ beta,
    float* __restrict__ out) {
  __shared__ float g[8 * C3_];
  int n0 = blockIdx.y * 8;
  int t = threadIdx.x;
  for (int e = t; e < 8 * C3_; e += 256)
    g[e] = gap[n0 * C3_ + e] * (1.f / 3600.f);
  __syncthreads();
  int o = blockIdx.x * 256 + t;
  const float* wr = wh + (long)o * C3_;
  float acc[8];
#pragma unroll
  for (int i = 0; i < 8; i++) acc[i] = 0.f;
#pragma unroll 4
  for (int c = 0; c < C3_; c += 4) {
    float4 wv = *(const float4*)(wr + c);
#pragma unroll
    for (int i = 0; i < 8; i++) {
      const float* gi = g + i * C3_ + c;
      acc[i] = fmaf(wv.x, gi[0], acc[i]);
      acc[i] = fmaf(wv.y, gi[1], acc[i]);
      acc[i] = fmaf(wv.z, gi[2], acc[i]);
      acc[i] = fmaf(wv.w, gi[3], acc[i]);
    }
  }
  float al = alpha[o], be = beta[o];
#pragma unroll
  for (int i = 0; i < 8; i++)
    out[(n0 + i) * HEAD_ + o] = fmaxf(fmaf(acc[i], al, be), 0.f);
}

// ---------------------------------------------------------------------------
extern "C" void kernel_launch(void* const* d_in, const int* in_sizes, int n_in,
                              void* d_out, int out_size, void* d_ws,
                              size_t ws_size, hipStream_t stream) {
  const float* x      = (const float*)d_in[0];
  const float* w_stem = (const float*)d_in[1];
  const float* a_stem = (const float*)d_in[2];
  const float* b_stem = (const float*)d_in[3];
  const float* w1     = (const float*)d_in[4];
  const float* a1     = (const float*)d_in[5];
  const float* b1     = (const float*)d_in[6];
  const float* w2     = (const float*)d_in[7];
  const float* a2     = (const float*)d_in[8];
  const float* b2     = (const float*)d_in[9];
  const float* wh     = (const float*)d_in[10];
  const float* ah     = (const float*)d_in[11];
  const float* bh     = (const float*)d_in[12];
  float* out = (float*)d_out;

  US* h1q = (US*)d_ws;                                   // 64*122*3968
  US* wt1 = h1q + (size_t)N_ * 122 * H1Q_ROW;            // 9*64*32
  US* wt2 = wt1 + 9 * 64 * 32;                           // 128*64
  US* wt0 = wt2 + C3_ * C2_;                             // 32*32
  float* gap = (float*)(wt0 + 1024);                     // 64*128 f32

  {  // K0 prep
    int total = ZTOT + 18432 + 8192 + 1024 + 8192;
    k0_prep<<<(total + 255) / 256, 256, 0, stream>>>(w1, w2, w_stem, h1q,
                                                     wt1, wt2, wt0, gap);
  }
  {  // K1 MFMA stem: one block per (row, n), gld_lds staging
    dim3 grid(H1_, N_);
    k1_mfma<<<grid, 256, 0, stream>>>(x, wt0, a_stem, b_stem, h1q);
  }
  {  // K2 ring-8 counted-vmcnt pipelined conv2+conv3+GAP
    dim3 grid(8, N_);
    k2_fused<<<grid, 256, 0, stream>>>(h1q, wt1, wt2, a1, b1, a2, b2, gap);
  }
  {  // K4: 8 n's per block, wh reused
    dim3 grid(HEAD_ / 256, 8);
    k4_head<<<grid, 256, 0, stream>>>(gap, wh, ah, bh, out);
  }
}

// Round 8
// 149.108 us; speedup vs baseline: 1.0121x; 1.0111x over previous
//
#include <hip/hip_runtime.h>

#define N_    64
#define HW_   240
#define H1_   120
#define H2_   60
#define C0_   3
#define C1_   32
#define C2_   64
#define C3_   128
#define HEAD_ 1280

typedef unsigned short US;
typedef short bf16x8 __attribute__((ext_vector_type(8)));
typedef float f32x16 __attribute__((ext_vector_type(16)));

__device__ __forceinline__ US f2bf(float f) {
  union { float f; unsigned u; } v; v.f = f;
  unsigned r = v.u + 0x7FFF + ((v.u >> 16) & 1);  // RNE
  return (US)(r >> 16);
}

// h1q parity-split padded NHWC bf16: [n][row 122][parity 2][xh 62][32ch].
// h1 pixel (gy,gx): row = gy+1; gx even=2m -> plane0[m]; gx odd=2m-1 -> plane1[m].
// Pad liveness (audited R8): k2 reads rows 0..120 only (row 121 never read);
// live pad cells = row 0 (all) + p1 m=0 chunk of rows 1..120. Both are now
// written by k1; k0 no longer touches h1q.
#define H1Q_ROW 3968
#define H1Q_PL  1984

__device__ __forceinline__ void gld_lds16(const void* g, void* l) {
  __builtin_amdgcn_global_load_lds(
      (const __attribute__((address_space(1))) unsigned int*)g,
      (__attribute__((address_space(3))) unsigned int*)l, 16, 0, 0);
}

// ---------------------------------------------------------------------------
// K0 (R8): weight prep + gap zero ONLY. w1 -> wt1 [ky][kx][oc][ic] bf16;
// w2 -> wt2 [oc][ic] bf16; w_stem -> wt0 [oc][k32] bf16 (k>=27 zero).
// ---------------------------------------------------------------------------
__global__ __launch_bounds__(256) void k0_prep(
    const float* __restrict__ w1, const float* __restrict__ w2,
    const float* __restrict__ w0,
    US* __restrict__ wt1, US* __restrict__ wt2,
    US* __restrict__ wt0, float* __restrict__ gap) {
  int gid = blockIdx.x * 256 + threadIdx.x;
  if (gid < 18432) {
    int e = gid;                              // w1 flat [oc][ic][ky][kx]
    int oc = e / 288, ic = (e / 9) % 32, ky = (e / 3) % 3, kx = e % 3;
    wt1[((ky * 3 + kx) * 64 + oc) * 32 + ic] = f2bf(w1[e]);
  } else if (gid < 18432 + 8192) {
    int e = gid - 18432;
    wt2[e] = f2bf(w2[e]);
  } else if (gid < 18432 + 8192 + 1024) {
    int e = gid - (18432 + 8192);             // e = oc*32 + k
    int oc = e >> 5, k = e & 31;
    wt0[e] = (k < 27) ? f2bf(w0[oc * 27 + k]) : (US)0;
  } else if (gid < 18432 + 8192 + 1024 + 8192) {
    gap[gid - (18432 + 8192 + 1024)] = 0.f;
  }
}

// ---------------------------------------------------------------------------
// K1 (R8 = R18 + pad-writing): stem conv 3->32 via MFMA im2col, 1 output
// row per block, global_load_lds x staging. Grid (121, 64): blocks y<120
// compute row y+1 and also zero that row's p1 m=0 pad chunk; block y==120
// zeroes pad row 0 of its n and exits. Math bit-identical to R18.
// ---------------------------------------------------------------------------
#define XSW 248
__global__ __launch_bounds__(256) void k1_mfma(
    const float* __restrict__ x, const US* __restrict__ wt0,
    const float* __restrict__ alpha, const float* __restrict__ beta,
    US* __restrict__ h1q) {
  __shared__ __align__(16) float xs[3 * 3 * XSW];  // [seg=ic*3+r][248]
  __shared__ US ot[128 * 32];         // [px][oc] bf16
  int y = blockIdx.x, n = blockIdx.y;
  int t = threadIdx.x, w = t >> 6, l = t & 63;

  if (y == 120) {                     // zero pad row 0 (whole row, 3968 US)
    uint4 z; z.x = z.y = z.z = z.w = 0u;
    long base = (long)(n * 122) * H1Q_ROW;
    for (int u = t; u < 496; u += 256)
      *(uint4*)(h1q + base + (long)u * 8) = z;
    return;
  }

  long rowb = ((long)(n * 122 + y + 1)) * H1Q_ROW;
  if (t < 4) {                        // zero own row's p1 m=0 pad chunk
    uint4 z; z.x = z.y = z.z = z.w = 0u;
    *(uint4*)(h1q + rowb + H1Q_PL + t * 8) = z;
  }

  int iy0 = 2 * y - 1;
  const float* xn = x + (long)n * C0_ * HW_ * HW_;

  // boundary zeros: cols 0..3 and 244..247 per seg
  if (t < 18) {
    int seg = t >> 1, end = t & 1;
    float4 z; z.x = z.y = z.z = z.w = 0.f;
    *(float4*)(xs + seg * XSW + (end ? 244 : 0)) = z;
  }
  // iy<0 rows (only y==0, segs r==0): pre-zero interior
  if (y == 0) {
    float4 z; z.x = z.y = z.z = z.w = 0.f;
    for (int e = t; e < 180; e += 256) {
      int m = e % 60, icz = e / 60;
      *(float4*)(xs + (icz * 3) * XSW + 4 + 4 * m) = z;
    }
  }
  __syncthreads();   // zeros visible before async staging overlaps

  // async stage: seg (wave-uniform) = w, w+4, w+8; 60 lanes x 16 B each
  for (int sgi = w; sgi < 9; sgi += 4) {
    int ic = sgi / 3, r = sgi - (sgi / 3) * 3;
    int iy = iy0 + r;                  // wave-uniform
    if (iy >= 0 && l < 60)
      gld_lds16((const char*)(xn + (long)ic * HW_ * HW_ + (long)iy * HW_) +
                    l * 16,
                (char*)(xs + sgi * XSW + 4) + l * 16);
  }
  __syncthreads();   // drains vmcnt

  int wv = w;
  int lane31 = l & 31, half = l >> 5;
  int ox = wv * 32 + lane31;
  int oxc = ox < H1_ ? ox : (H1_ - 1);

  // A fragments: k = m*16 + half*8 + j; value = xs[seg(k)][3 + 2*oxc + kx]
  float fa[16];
#pragma unroll
  for (int m = 0; m < 2; m++)
#pragma unroll
    for (int j = 0; j < 8; j++) {
      int k = m * 16 + half * 8 + j;
      float v = 0.f;
      if (k < 27) {
        int ic = k / 9, rem = k - ic * 9;
        int ky = rem / 3, kx = rem - ky * 3;
        v = xs[(ic * 3 + ky) * XSW + 3 + 2 * oxc + kx];
      }
      fa[m * 8 + j] = v;
    }
  bf16x8 a0, a1;
#pragma unroll
  for (int j = 0; j < 8; j++) {
    a0[j] = (short)f2bf(fa[j]);
    a1[j] = (short)f2bf(fa[8 + j]);
  }
  const US* wb = wt0 + lane31 * 32 + half * 8;   // oc = lane31
  bf16x8 b0 = *(const bf16x8*)(wb);
  bf16x8 b1 = *(const bf16x8*)(wb + 16);

  f32x16 acc;
#pragma unroll
  for (int i = 0; i < 16; i++) acc[i] = 0.f;
  acc = __builtin_amdgcn_mfma_f32_32x32x16_bf16(a0, b0, acc, 0, 0, 0);
  acc = __builtin_amdgcn_mfma_f32_32x32x16_bf16(a1, b1, acc, 0, 0, 0);

  int oc = lane31;
  float al = alpha[oc], be = beta[oc];
#pragma unroll
  for (int r = 0; r < 16; r++) {
    int row = (r & 3) + 8 * (r >> 2) + 4 * half;   // px within tile
    float v = fmaxf(fmaf(acc[r], al, be), 0.f);
    ot[(wv * 32 + row) * 32 + oc] = f2bf(v);
  }
  __syncthreads();

  // store 120 px * 64 B as parity-split full chunks; 480 uint4 total
  for (int u = t; u < 480; u += 256) {
    int px = u >> 2, q = u & 3;
    int pl = px & 1;
    int m = (px + 1) >> 1;
    long addr = rowb + (pl ? H1Q_PL : 0) + (long)m * 32 + q * 8;
    *(uint4*)(h1q + addr) = *(const uint4*)(ot + px * 32 + q * 8);
  }
}

// ---------------------------------------------------------------------------
// K2 (R16/R5 exact — best known): persistent-row pipelined fused
// conv2+conv3+GAP. grid (8,64) = 512 blocks = 2/CU. LDS ring of 6 row-slots,
// 8192 B each; staging padded to 512 chunks (8 KB) per row (wave-uniform
// {row, slot}). All weights hoisted to registers; main loop has zero global
// loads. (R20's counted-vmcnt variant was +2 us — reverted.)
// ---------------------------------------------------------------------------
#define TS 72
__global__ __launch_bounds__(256, 2) void k2_fused(
    const US* __restrict__ h1q, const US* __restrict__ wt1,
    const US* __restrict__ wt2,
    const float* __restrict__ a1, const float* __restrict__ b1,
    const float* __restrict__ a2, const float* __restrict__ b2,
    float* __restrict__ gap) {
  __shared__ __align__(16) US st[6 * 4096];    // 49152 B: 6 row-slots (swz)
  __shared__ __align__(16) US tile[64 * TS];   // 9216 B: conv2 out [px][oc]
  int t = threadIdx.x, w = t >> 6, l = t & 63;
  int lane31 = l & 31, half = l >> 5;

  // XCD x (= blockIdx.x, x-major dispatch) handles n in [8x, 8x+8)
  int n = 8 * blockIdx.x + (blockIdx.y & 7);
  int bxr = blockIdx.y >> 3;                   // row-group 0..7
  int ny = bxr < 4 ? 8 : 7;
  int y0 = bxr < 4 ? bxr * 8 : 32 + (bxr - 4) * 7;

  const char* nb = (const char*)(h1q + (long)(n * 122) * H1Q_ROW);

  // ---- hoist all weights / BN params to registers (loop-invariant) ----
  int wm = w & 1, wn = w >> 1;                 // stage-A roles
  int oc = wn * 32 + lane31;
  int pt = w & 1, og = w >> 1;                 // conv3 roles
  bf16x8 wA[9][2];
#pragma unroll
  for (int kk = 0; kk < 9; kk++)
#pragma unroll
    for (int c = 0; c < 2; c++)
      wA[kk][c] = *(const bf16x8*)(wt1 + (kk * 64 + oc) * 32 + half * 8 + c * 16);
  bf16x8 wB[2][4];
  float al2[2], be2[2];
#pragma unroll
  for (int nt = 0; nt < 2; nt++) {
    int oc2 = (og * 2 + nt) * 32 + lane31;
#pragma unroll
    for (int c = 0; c < 4; c++)
      wB[nt][c] = *(const bf16x8*)(wt2 + oc2 * 64 + half * 8 + c * 16);
    al2[nt] = a2[oc2]; be2[nt] = b2[oc2];
  }
  float al1 = a1[oc], be1 = b1[oc];

  // per-thread invariant A-read offsets (swizzled, within-row US units)
  int px = wm * 32 + lane31;
  int xx = px < 60 ? px : 59;
  int abase = xx * 32 + half * 8;
  int usofs[3][2];
#pragma unroll
  for (int kx = 0; kx < 3; kx++)
#pragma unroll
    for (int c = 0; c < 2; c++) {
      int uo = (kx == 1 ? 0 : (kx == 0 ? 1984 : 2016)) + abase + c * 16;
      usofs[kx][c] = uo ^ (((uo >> 6) & 7) << 3);
    }

  // ---- prologue: stage rows 2y0..2y0+2, 512 chunks (8 KB) per row ----
#pragma unroll
  for (int i = 0; i < 6; i++) {
    int c = i * 256 + t;                  // 1536 = 3 rows * 512 chunks
    int rw = c >> 9;                      // wave-uniform (512 % 64 == 0)
    int b = (c & 511) * 16;
    int sb = b ^ (((b >> 7) & 7) << 4);
    int r = 2 * y0 + rw;
    gld_lds16(nb + (long)r * 7936 + sb, (char*)st + (r % 6) * 8192 + b);
  }
  __syncthreads();

  for (int iy = 0; iy < ny; iy++) {
    int y = y0 + iy;
    // ---- issue next-2-row stage early (hidden under stage-A MFMAs) ----
    if (iy + 1 < ny) {
#pragma unroll
      for (int i = 0; i < 4; i++) {
        int c = i * 256 + t;              // 1024 = 2 rows * 512 chunks
        int rw = c >> 9;                  // wave-uniform
        int b = (c & 511) * 16;
        int sb = b ^ (((b >> 7) & 7) << 4);
        int r = 2 * y + 3 + rw;           // rows 2y+3, 2y+4 (slots disjoint
        gld_lds16(nb + (long)r * 7936 + sb,  // from compute rows 2y..2y+2)
                  (char*)st + (r % 6) * 8192 + b);
      }
    }

    // ---- stage A: conv2 3x3 s2, 32->64, from LDS ring ----
    f32x16 acc;
#pragma unroll
    for (int i = 0; i < 16; i++) acc[i] = 0.f;
#pragma unroll
    for (int ky = 0; ky < 3; ky++) {
      int r = 2 * y + ky;
      int sb6 = (r % 6) * 4096;
#pragma unroll
      for (int kx = 0; kx < 3; kx++) {
#pragma unroll
        for (int c = 0; c < 2; c++) {
          bf16x8 av = *(const bf16x8*)(st + sb6 + usofs[kx][c]);
          acc = __builtin_amdgcn_mfma_f32_32x32x16_bf16(av, wA[ky * 3 + kx][c],
                                                        acc, 0, 0, 0);
        }
      }
    }
#pragma unroll
    for (int r = 0; r < 16; r++) {
      int row = (r & 3) + 8 * (r >> 2) + 4 * half;
      tile[(wm * 32 + row) * TS + oc] = f2bf(fmaxf(fmaf(acc[r], al1, be1), 0.f));
    }
    __syncthreads();   // tile ready; also drains prefetch vmcnt (has cover)

    // ---- conv3 1x1 64->128 + BN/ReLU + GAP ----
    const US* ab = tile + (pt * 32 + lane31) * TS + half * 8;
    bf16x8 af[4];
#pragma unroll
    for (int c = 0; c < 4; c++) af[c] = *(const bf16x8*)(ab + c * 16);

#pragma unroll
    for (int nt = 0; nt < 2; nt++) {
      int oc2 = (og * 2 + nt) * 32 + lane31;
      f32x16 acc2;
#pragma unroll
      for (int i = 0; i < 16; i++) acc2[i] = 0.f;
#pragma unroll
      for (int c = 0; c < 4; c++)
        acc2 = __builtin_amdgcn_mfma_f32_32x32x16_bf16(af[c], wB[nt][c], acc2,
                                                       0, 0, 0);
      float s = 0.f;
      if (pt == 0) {
#pragma unroll
        for (int r = 0; r < 16; r++) s += fmaxf(fmaf(acc2[r], al2[nt], be2[nt]), 0.f);
      } else {
#pragma unroll
        for (int r = 0; r < 16; r++) {
          int row = (r & 3) + 8 * (r >> 2) + 4 * half;
          if (32 + row < 60) s += fmaxf(fmaf(acc2[r], al2[nt], be2[nt]), 0.f);
        }
      }
      s += __shfl_xor(s, 32);
      if (half == 0) atomicAdd(gap + n * C3_ + oc2, s);
    }
    __syncthreads();   // protect tile + ring slots for next iteration
  }
}

// ---------------------------------------------------------------------------
// K4 (R15, unchanged): head — 8 n's per block, wh reused. grid (5, 8).
// ---------------------------------------------------------------------------
__global__ __launch_bounds__(256) void k4_head(
    const float* __restrict__ gap, const float* __restrict__ wh,
    const float* __restrict__ alpha, const float* __restrict__ beta,
    float* __restrict__ out) {
  __shared__ float g[8 * C3_];
  int n0 = blockIdx.y * 8;
  int t = threadIdx.x;
  for (int e = t; e < 8 * C3_; e += 256)
    g[e] = gap[n0 * C3_ + e] * (1.f / 3600.f);
  __syncthreads();
  int o = blockIdx.x * 256 + t;
  const float* wr = wh + (long)o * C3_;
  float acc[8];
#pragma unroll
  for (int i = 0; i < 8; i++) acc[i] = 0.f;
#pragma unroll 4
  for (int c = 0; c < C3_; c += 4) {
    float4 wv = *(const float4*)(wr + c);
#pragma unroll
    for (int i = 0; i < 8; i++) {
      const float* gi = g + i * C3_ + c;
      acc[i] = fmaf(wv.x, gi[0], acc[i]);
      acc[i] = fmaf(wv.y, gi[1], acc[i]);
      acc[i] = fmaf(wv.z, gi[2], acc[i]);
      acc[i] = fmaf(wv.w, gi[3], acc[i]);
    }
  }
  float al = alpha[o], be = beta[o];
#pragma unroll
  for (int i = 0; i < 8; i++)
    out[(n0 + i) * HEAD_ + o] = fmaxf(fmaf(acc[i], al, be), 0.f);
}

// ---------------------------------------------------------------------------
extern "C" void kernel_launch(void* const* d_in, const int* in_sizes, int n_in,
                              void* d_out, int out_size, void* d_ws,
                              size_t ws_size, hipStream_t stream) {
  const float* x      = (const float*)d_in[0];
  const float* w_stem = (const float*)d_in[1];
  const float* a_stem = (const float*)d_in[2];
  const float* b_stem = (const float*)d_in[3];
  const float* w1     = (const float*)d_in[4];
  const float* a1     = (const float*)d_in[5];
  const float* b1     = (const float*)d_in[6];
  const float* w2     = (const float*)d_in[7];
  const float* a2     = (const float*)d_in[8];
  const float* b2     = (const float*)d_in[9];
  const float* wh     = (const float*)d_in[10];
  const float* ah     = (const float*)d_in[11];
  const float* bh     = (const float*)d_in[12];
  float* out = (float*)d_out;

  US* h1q = (US*)d_ws;                                   // 64*122*3968
  US* wt1 = h1q + (size_t)N_ * 122 * H1Q_ROW;            // 9*64*32
  US* wt2 = wt1 + 9 * 64 * 32;                           // 128*64
  US* wt0 = wt2 + C3_ * C2_;                             // 32*32
  float* gap = (float*)(wt0 + 1024);                     // 64*128 f32

  {  // K0: weights + gap only (h1q pads handled by k1)
    int total = 18432 + 8192 + 1024 + 8192;              // 35840
    k0_prep<<<(total + 255) / 256, 256, 0, stream>>>(w1, w2, w_stem,
                                                     wt1, wt2, wt0, gap);
  }
  {  // K1 MFMA stem + pad writes: grid (121, 64)
    dim3 grid(H1_ + 1, N_);
    k1_mfma<<<grid, 256, 0, stream>>>(x, wt0, a_stem, b_stem, h1q);
  }
  {  // K2 persistent-row pipelined conv2+conv3+GAP (R16 exact)
    dim3 grid(8, N_);
    k2_fused<<<grid, 256, 0, stream>>>(h1q, wt1, wt2, a1, b1, a2, b2, gap);
  }
  {  // K4: 8 n's per block, wh reused
    dim3 grid(HEAD_ / 256, 8);
    k4_head<<<grid, 256, 0, stream>>>(gap, wh, ah, bh, out);
  }
}